// Round 8
// baseline (145.491 us; speedup 1.0000x reference)
//
#include <hip/hip_runtime.h>
#include <hip/hip_bf16.h>

// CriticREM: out = relu(relu([state|action]W1^T+b1)W2^T+b2) @ Wc^T + bc
//   Wc = sum_h alpha_h * Wh[h], bc = sum_h alpha_h * bh[h]
// B=65536, IN=128, HID=256, NUM_HEADS=200, OUT=1
//
// R8: R7 transposed-GEMM + register-resident weights, restructured into a
//     1-barrier-per-tile software pipeline:
//   phase(t) = [ GEMM1(t) -> epi1 -> h1s[t&1] ] || [ GEMM2(t-1) from
//   h1s[(t-1)&1] -> epi2 -> sPart[(t-1)&1] ] || [ xs stage(t+1) ] ||
//   [ out-write(t-2) from sPart[(t-2)&1] ], then ONE __syncthreads.
//   All cross-wave deps cross exactly one barrier (xs/h1s/sPart all
//   parity double-buffered). Barriers/block: 12 -> 6.
//   LDS 104.4KB -> dynamic smem + hipFuncSetAttribute (host-side, graph-safe).
//   VGPR ~230 under the (512,2)=256 cap so weight frags stay resident.

#define B_TOTAL 65536
#define SDIM 96
#define ADIM 32
#define IN_F 128
#define HID 256
#define NHEADS 200
#define BM 64           // batch rows per tile
#define NTILES 4        // tiles per block (grid 256 = 1 block/CU)
#define XS_PITCH 132    // 66 dw row stride == 2 mod 32: balanced b128 (measured R2-class)
#define H1_PITCH 260    // 130 dw == 2 mod 32: measured 0 conflicts (R2)
#define XS_ELEMS (BM * XS_PITCH)   // 8448
#define H1_ELEMS (BM * H1_PITCH)   // 16640
#define SMEM_BYTES (2 * XS_ELEMS * 2 + 2 * H1_ELEMS * 2 + 2 * 8 * BM * 4)  // 104448

typedef __bf16 bf16;
typedef __attribute__((ext_vector_type(4))) __bf16 bf16x4;
typedef __attribute__((ext_vector_type(8))) __bf16 bf16x8;
typedef __attribute__((ext_vector_type(4))) float f32x4;

// ---- prep: W1,W2 -> bf16 in ws; collapse heads: Wc[256], bc (fp32) ----
__global__ void prep_kernel(const float* __restrict__ W1, const float* __restrict__ W2,
                            const float* __restrict__ alphas, const float* __restrict__ Wh,
                            const float* __restrict__ bh,
                            bf16* __restrict__ W1bf, bf16* __restrict__ W2bf,
                            float* __restrict__ Wc) {
    int tid = blockIdx.x * blockDim.x + threadIdx.x;
    if (tid < IN_F * HID) W1bf[tid] = (bf16)W1[tid];
    if (tid < HID * HID)  W2bf[tid] = (bf16)W2[tid];
    if (tid < HID) {
        float acc = 0.f;
        #pragma unroll 8
        for (int h = 0; h < NHEADS; ++h) acc += alphas[h] * Wh[h * HID + tid];
        Wc[tid] = acc;
    }
    if (tid == HID) {
        float acc = 0.f;
        for (int h = 0; h < NHEADS; ++h) acc += alphas[h] * bh[h];
        Wc[HID] = acc;   // bc
    }
}

// ---- main fused kernel: 512 threads (8 waves), pipelined over 4 tiles ----
__global__ __launch_bounds__(512, 2) void critic_kernel(
        const float* __restrict__ state, const float* __restrict__ action,
        const float* __restrict__ b1, const float* __restrict__ b2,
        const bf16* __restrict__ W1bf, const bf16* __restrict__ W2bf,
        const float* __restrict__ Wc, float* __restrict__ out) {

    extern __shared__ char smem[];
    bf16*  xs    = (bf16*)smem;                                   // [2][XS_ELEMS]
    bf16*  h1s   = (bf16*)(smem + 2 * XS_ELEMS * 2);              // [2][H1_ELEMS]
    float* sPart = (float*)(smem + 2 * XS_ELEMS * 2 + 2 * H1_ELEMS * 2); // [2][8][BM]

    const int tid  = threadIdx.x;
    const int wave = tid >> 6;      // 0..7
    const int lane = tid & 63;
    const int q    = lane >> 4;     // 0..3
    const int ln   = lane & 15;     // 0..15
    const int colw = wave * 32;     // this wave's 32-hidden-col slice
    const int brow0 = blockIdx.x * (BM * NTILES);

    // ---- preamble: ALL weight fragments into registers, once per block ----
    bf16x8 w1f[4][2];   // 32 VGPR
    #pragma unroll
    for (int ks = 0; ks < 4; ++ks)
        #pragma unroll
        for (int nt = 0; nt < 2; ++nt)
            w1f[ks][nt] = *(const bf16x8*)&W1bf[(size_t)(colw + nt * 16 + ln) * IN_F + ks * 32 + q * 8];

    bf16x8 w2f[8][2];   // 64 VGPR
    #pragma unroll
    for (int ks = 0; ks < 8; ++ks)
        #pragma unroll
        for (int nt = 0; nt < 2; ++nt)
            w2f[ks][nt] = *(const bf16x8*)&W2bf[(size_t)(colw + nt * 16 + ln) * HID + ks * 32 + q * 8];

    // epilogue constants: hidden col n = colw + nt*16 + q*4 + r -> float4 loads
    f32x4 b1v[2], b2v[2], wcv[2];
    #pragma unroll
    for (int nt = 0; nt < 2; ++nt) {
        const int n4 = colw + nt * 16 + q * 4;
        b1v[nt] = *(const f32x4*)&b1[n4];
        b2v[nt] = *(const f32x4*)&b2[n4];
        wcv[nt] = *(const f32x4*)&Wc[n4];
    }
    const float bc = Wc[HID];

    // ---- x staging helper state: 512 threads x 2 chunks of 8 fp32 ----
    float4 px[2][2];
    const int c0r  = tid >> 4;          // chunk 0 row
    const int c0c8 = tid & 15;
    const int c1r  = (tid + 512) >> 4;  // chunk 1 row
    const int c1c8 = (tid + 512) & 15;

    // load px(tile 0), write xs[0], load px(tile 1)
    {
        const float* s0 = (c0c8 < 12) ? (state  + (size_t)(brow0 + c0r) * SDIM + c0c8 * 8)
                                      : (action + (size_t)(brow0 + c0r) * ADIM + (c0c8 - 12) * 8);
        const float* s1 = (c1c8 < 12) ? (state  + (size_t)(brow0 + c1r) * SDIM + c1c8 * 8)
                                      : (action + (size_t)(brow0 + c1r) * ADIM + (c1c8 - 12) * 8);
        px[0][0] = ((const float4*)s0)[0]; px[0][1] = ((const float4*)s0)[1];
        px[1][0] = ((const float4*)s1)[0]; px[1][1] = ((const float4*)s1)[1];
        bf16x8 v0 = (bf16x8){(bf16)px[0][0].x, (bf16)px[0][0].y, (bf16)px[0][0].z, (bf16)px[0][0].w,
                             (bf16)px[0][1].x, (bf16)px[0][1].y, (bf16)px[0][1].z, (bf16)px[0][1].w};
        bf16x8 v1 = (bf16x8){(bf16)px[1][0].x, (bf16)px[1][0].y, (bf16)px[1][0].z, (bf16)px[1][0].w,
                             (bf16)px[1][1].x, (bf16)px[1][1].y, (bf16)px[1][1].z, (bf16)px[1][1].w};
        *(bf16x8*)&xs[c0r * XS_PITCH + c0c8 * 8] = v0;
        *(bf16x8*)&xs[c1r * XS_PITCH + c1c8 * 8] = v1;
        // prefetch tile 1
        const int n0 = brow0 + BM;
        const float* t0 = (c0c8 < 12) ? (state  + (size_t)(n0 + c0r) * SDIM + c0c8 * 8)
                                      : (action + (size_t)(n0 + c0r) * ADIM + (c0c8 - 12) * 8);
        const float* t1 = (c1c8 < 12) ? (state  + (size_t)(n0 + c1r) * SDIM + c1c8 * 8)
                                      : (action + (size_t)(n0 + c1r) * ADIM + (c1c8 - 12) * 8);
        px[0][0] = ((const float4*)t0)[0]; px[0][1] = ((const float4*)t0)[1];
        px[1][0] = ((const float4*)t1)[0]; px[1][1] = ((const float4*)t1)[1];
    }
    __syncthreads();

    // ---- pipelined phases: t = 0..NTILES ----
    #pragma unroll
    for (int t = 0; t <= NTILES; ++t) {
        // --- GEMM1(t): read xs[t&1], epi1 -> h1s[t&1] ---
        if (t < NTILES) {
            const bf16* xsb = xs  + (t & 1) * XS_ELEMS;
            bf16*       h1b = h1s + (t & 1) * H1_ELEMS;

            f32x4 acc1[4][2];
            #pragma unroll
            for (int mt = 0; mt < 4; ++mt)
                #pragma unroll
                for (int nt = 0; nt < 2; ++nt)
                    acc1[mt][nt] = (f32x4){0.f, 0.f, 0.f, 0.f};

            #pragma unroll
            for (int ks = 0; ks < 4; ++ks) {
                const int k0 = ks * 32 + q * 8;
                bf16x8 bfr[4];
                #pragma unroll
                for (int mt = 0; mt < 4; ++mt)
                    bfr[mt] = *(const bf16x8*)&xsb[(mt * 16 + ln) * XS_PITCH + k0];
                #pragma unroll
                for (int mt = 0; mt < 4; ++mt)
                    #pragma unroll
                    for (int nt = 0; nt < 2; ++nt)
                        acc1[mt][nt] = __builtin_amdgcn_mfma_f32_16x16x32_bf16(w1f[ks][nt], bfr[mt], acc1[mt][nt], 0, 0, 0);
            }
            #pragma unroll
            for (int nt = 0; nt < 2; ++nt)
                #pragma unroll
                for (int mt = 0; mt < 4; ++mt) {
                    bf16x4 v4;
                    #pragma unroll
                    for (int r = 0; r < 4; ++r) {
                        float v = acc1[mt][nt][r] + b1v[nt][r];
                        v = v > 0.f ? v : 0.f;
                        v4[r] = (bf16)v;
                    }
                    *(bf16x4*)&h1b[(mt * 16 + ln) * H1_PITCH + colw + nt * 16 + q * 4] = v4;
                }

            // stage xs for tile t+1 from px regs; then prefetch px for t+2
            if (t + 1 < NTILES) {
                bf16* xsn = xs + ((t + 1) & 1) * XS_ELEMS;
                bf16x8 v0 = (bf16x8){(bf16)px[0][0].x, (bf16)px[0][0].y, (bf16)px[0][0].z, (bf16)px[0][0].w,
                                     (bf16)px[0][1].x, (bf16)px[0][1].y, (bf16)px[0][1].z, (bf16)px[0][1].w};
                bf16x8 v1 = (bf16x8){(bf16)px[1][0].x, (bf16)px[1][0].y, (bf16)px[1][0].z, (bf16)px[1][0].w,
                                     (bf16)px[1][1].x, (bf16)px[1][1].y, (bf16)px[1][1].z, (bf16)px[1][1].w};
                *(bf16x8*)&xsn[c0r * XS_PITCH + c0c8 * 8] = v0;
                *(bf16x8*)&xsn[c1r * XS_PITCH + c1c8 * 8] = v1;
            }
            if (t + 2 < NTILES) {
                const int n0 = brow0 + (t + 2) * BM;
                const float* t0 = (c0c8 < 12) ? (state  + (size_t)(n0 + c0r) * SDIM + c0c8 * 8)
                                              : (action + (size_t)(n0 + c0r) * ADIM + (c0c8 - 12) * 8);
                const float* t1 = (c1c8 < 12) ? (state  + (size_t)(n0 + c1r) * SDIM + c1c8 * 8)
                                              : (action + (size_t)(n0 + c1r) * ADIM + (c1c8 - 12) * 8);
                px[0][0] = ((const float4*)t0)[0]; px[0][1] = ((const float4*)t0)[1];
                px[1][0] = ((const float4*)t1)[0]; px[1][1] = ((const float4*)t1)[1];
            }
        }

        // --- GEMM2(t-1): read h1s[(t-1)&1], epi2 -> sPart[(t-1)&1] ---
        if (t >= 1) {
            const bf16* h1b = h1s + ((t - 1) & 1) * H1_ELEMS;

            f32x4 acc2[4][2];
            #pragma unroll
            for (int mt = 0; mt < 4; ++mt)
                #pragma unroll
                for (int nt = 0; nt < 2; ++nt)
                    acc2[mt][nt] = (f32x4){0.f, 0.f, 0.f, 0.f};

            #pragma unroll
            for (int ks = 0; ks < 8; ++ks) {
                const int k0 = ks * 32 + q * 8;
                bf16x8 bfr[4];
                #pragma unroll
                for (int mt = 0; mt < 4; ++mt)
                    bfr[mt] = *(const bf16x8*)&h1b[(mt * 16 + ln) * H1_PITCH + k0];
                #pragma unroll
                for (int mt = 0; mt < 4; ++mt)
                    #pragma unroll
                    for (int nt = 0; nt < 2; ++nt)
                        acc2[mt][nt] = __builtin_amdgcn_mfma_f32_16x16x32_bf16(w2f[ks][nt], bfr[mt], acc2[mt][nt], 0, 0, 0);
            }

            float partial[4];
            #pragma unroll
            for (int mt = 0; mt < 4; ++mt) {
                float p = 0.f;
                #pragma unroll
                for (int nt = 0; nt < 2; ++nt)
                    #pragma unroll
                    for (int r = 0; r < 4; ++r) {
                        float v = acc2[mt][nt][r] + b2v[nt][r];
                        v = v > 0.f ? v : 0.f;
                        p += v * wcv[nt][r];
                    }
                partial[mt] = p;
            }
            #pragma unroll
            for (int mt = 0; mt < 4; ++mt) {
                partial[mt] += __shfl_xor(partial[mt], 16, 64);
                partial[mt] += __shfl_xor(partial[mt], 32, 64);
            }
            if (q == 0) {
                float* sp = sPart + ((t - 1) & 1) * (8 * BM) + wave * BM;
                #pragma unroll
                for (int mt = 0; mt < 4; ++mt)
                    sp[mt * 16 + ln] = partial[mt];
            }
        }

        // --- out-write(t-2) from sPart[(t-2)&1] ---
        if (t >= 2) {
            if (tid < BM) {
                const float* sp = sPart + ((t - 2) & 1) * (8 * BM);
                float v = bc;
                #pragma unroll
                for (int w = 0; w < 8; ++w) v += sp[w * BM + tid];
                out[brow0 + (t - 2) * BM + tid] = v;
            }
        }

        __syncthreads();
    }

    // final out(NTILES-1)
    if (tid < BM) {
        const float* sp = sPart + ((NTILES - 1) & 1) * (8 * BM);
        float v = bc;
        #pragma unroll
        for (int w = 0; w < 8; ++w) v += sp[w * BM + tid];
        out[brow0 + (NTILES - 1) * BM + tid] = v;
    }
}

extern "C" void kernel_launch(void* const* d_in, const int* in_sizes, int n_in,
                              void* d_out, int out_size, void* d_ws, size_t ws_size,
                              hipStream_t stream) {
    const float* state  = (const float*)d_in[0];
    const float* action = (const float*)d_in[1];
    const float* alphas = (const float*)d_in[2];
    const float* W1     = (const float*)d_in[3];
    const float* b1     = (const float*)d_in[4];
    const float* W2     = (const float*)d_in[5];
    const float* b2     = (const float*)d_in[6];
    const float* Wh     = (const float*)d_in[7];
    const float* bh     = (const float*)d_in[8];
    float* out = (float*)d_out;

    bf16*  W1bf = (bf16*)d_ws;                                  // 65536 B
    bf16*  W2bf = (bf16*)((char*)d_ws + 65536);                 // 131072 B
    float* Wc   = (float*)((char*)d_ws + 65536 + 131072);       // 257 * 4 B

    // allow >64KB dynamic LDS (host-side module state; idempotent; not a
    // stream op -> graph-capture safe)
    static bool attr_done = false;
    (void)hipFuncSetAttribute((const void*)critic_kernel,
                              hipFuncAttributeMaxDynamicSharedMemorySize,
                              SMEM_BYTES);

    prep_kernel<<<256, 256, 0, stream>>>(W1, W2, alphas, Wh, bh, W1bf, W2bf, Wc);
    critic_kernel<<<B_TOTAL / (BM * NTILES), 512, SMEM_BYTES, stream>>>(
        state, action, b1, b2, W1bf, W2bf, Wc, out);
}

// Round 9
// 119.648 us; speedup vs baseline: 1.2160x; 1.2160x over previous
//
#include <hip/hip_runtime.h>
#include <hip/hip_bf16.h>

// CriticREM: out = relu(relu([state|action]W1^T+b1)W2^T+b2) @ Wc^T + bc
//   Wc = sum_h alpha_h * Wh[h], bc = sum_h alpha_h * bh[h]
// B=65536, IN=128, HID=256, NUM_HEADS=200, OUT=1
//
// R9: R7's straightline transposed-GEMM body (the only shape where the
//     compiler provably keeps the 96-VGPR weight set resident), rescheduled:
//   - grid 512, NTILES=2: dynamic load balancing (R7's static grid=256 showed
//     ~20%<25% occupancy => uneven block/CU assignment => straggler tail).
//   - out-write(t-1) moved INTO the GEMM1 phase (sPart parity-buffered):
//     overlaps MFMA instead of owning its own barrier.
//   - next-tile x global loads issued BEFORE GEMM2, consumed after: ~400cy
//     L2/L3 latency hidden under 64 MFMAs.
//   - barriers: R7 3/tile -> 2/tile (+1 final).
//   NO phase conditionals around weight uses (R8's pipeline made the compiler
//   sink the weights: VGPR 124, 56us — R1-class regression).

#define B_TOTAL 65536
#define SDIM 96
#define ADIM 32
#define IN_F 128
#define HID 256
#define NHEADS 200
#define BM 64           // batch rows per tile
#define NTILES 2        // tiles per block (grid 512)
#define XS_PITCH 132    // 66 dw row stride == 2 mod 32: conflict-free class (R2)
#define H1_PITCH 260    // 130 dw == 2 mod 32: measured 0 conflicts (R2)

typedef __bf16 bf16;
typedef __attribute__((ext_vector_type(4))) __bf16 bf16x4;
typedef __attribute__((ext_vector_type(8))) __bf16 bf16x8;
typedef __attribute__((ext_vector_type(4))) float f32x4;

// ---- prep: W1,W2 -> bf16 in ws; collapse heads: Wc[256], bc (fp32) ----
__global__ void prep_kernel(const float* __restrict__ W1, const float* __restrict__ W2,
                            const float* __restrict__ alphas, const float* __restrict__ Wh,
                            const float* __restrict__ bh,
                            bf16* __restrict__ W1bf, bf16* __restrict__ W2bf,
                            float* __restrict__ Wc) {
    int tid = blockIdx.x * blockDim.x + threadIdx.x;
    if (tid < IN_F * HID) W1bf[tid] = (bf16)W1[tid];
    if (tid < HID * HID)  W2bf[tid] = (bf16)W2[tid];
    if (tid < HID) {
        float acc = 0.f;
        #pragma unroll 8
        for (int h = 0; h < NHEADS; ++h) acc += alphas[h] * Wh[h * HID + tid];
        Wc[tid] = acc;
    }
    if (tid == HID) {
        float acc = 0.f;
        for (int h = 0; h < NHEADS; ++h) acc += alphas[h] * bh[h];
        Wc[HID] = acc;   // bc
    }
}

// ---- main fused kernel: 512 threads (8 waves), 2 tiles of 64 rows ----
__global__ __launch_bounds__(512, 2) void critic_kernel(
        const float* __restrict__ state, const float* __restrict__ action,
        const float* __restrict__ b1, const float* __restrict__ b2,
        const bf16* __restrict__ W1bf, const bf16* __restrict__ W2bf,
        const float* __restrict__ Wc, float* __restrict__ out) {

    __shared__ bf16 xs[BM * XS_PITCH];     // 16896 B
    __shared__ bf16 h1s[BM * H1_PITCH];    // 33280 B
    __shared__ float sPart[2][8][BM];      // 4096 B  (parity-buffered)

    const int tid  = threadIdx.x;
    const int wave = tid >> 6;      // 0..7
    const int lane = tid & 63;
    const int q    = lane >> 4;     // 0..3
    const int ln   = lane & 15;     // 0..15
    const int colw = wave * 32;     // this wave's 32-hidden-col slice
    const int brow0 = blockIdx.x * (BM * NTILES);

    // ---- preamble: ALL weight fragments into registers, once per block ----
    bf16x8 w1f[4][2];   // 32 VGPR
    #pragma unroll
    for (int ks = 0; ks < 4; ++ks)
        #pragma unroll
        for (int nt = 0; nt < 2; ++nt)
            w1f[ks][nt] = *(const bf16x8*)&W1bf[(size_t)(colw + nt * 16 + ln) * IN_F + ks * 32 + q * 8];

    bf16x8 w2f[8][2];   // 64 VGPR
    #pragma unroll
    for (int ks = 0; ks < 8; ++ks)
        #pragma unroll
        for (int nt = 0; nt < 2; ++nt)
            w2f[ks][nt] = *(const bf16x8*)&W2bf[(size_t)(colw + nt * 16 + ln) * HID + ks * 32 + q * 8];

    // epilogue constants: hidden col n = colw + nt*16 + q*4 + r -> float4 loads
    f32x4 b1v[2], b2v[2], wcv[2];
    #pragma unroll
    for (int nt = 0; nt < 2; ++nt) {
        const int n4 = colw + nt * 16 + q * 4;
        b1v[nt] = *(const f32x4*)&b1[n4];
        b2v[nt] = *(const f32x4*)&b2[n4];
        wcv[nt] = *(const f32x4*)&Wc[n4];
    }
    const float bc = Wc[HID];

    // x staging geometry: 512 threads x 2 chunks of 8 fp32 (64 rows x 16 chunks)
    const int c0r  = tid >> 4;
    const int c0c8 = tid & 15;
    const int c1r  = (tid + 512) >> 4;
    const int c1c8 = (tid + 512) & 15;

    // ---- stage xs(0) ----
    {
        const float* s0 = (c0c8 < 12) ? (state  + (size_t)(brow0 + c0r) * SDIM + c0c8 * 8)
                                      : (action + (size_t)(brow0 + c0r) * ADIM + (c0c8 - 12) * 8);
        const float* s1 = (c1c8 < 12) ? (state  + (size_t)(brow0 + c1r) * SDIM + c1c8 * 8)
                                      : (action + (size_t)(brow0 + c1r) * ADIM + (c1c8 - 12) * 8);
        float4 a0 = ((const float4*)s0)[0], a1 = ((const float4*)s0)[1];
        float4 b0 = ((const float4*)s1)[0], b1_ = ((const float4*)s1)[1];
        *(bf16x8*)&xs[c0r * XS_PITCH + c0c8 * 8] =
            (bf16x8){(bf16)a0.x, (bf16)a0.y, (bf16)a0.z, (bf16)a0.w,
                     (bf16)a1.x, (bf16)a1.y, (bf16)a1.z, (bf16)a1.w};
        *(bf16x8*)&xs[c1r * XS_PITCH + c1c8 * 8] =
            (bf16x8){(bf16)b0.x, (bf16)b0.y, (bf16)b0.z, (bf16)b0.w,
                     (bf16)b1_.x, (bf16)b1_.y, (bf16)b1_.z, (bf16)b1_.w};
    }
    __syncthreads();   // B_a(0)

    for (int t = 0; t < NTILES; ++t) {
        // --- out-write(t-1): overlaps GEMM1, reads sPart[(t-1)&1] (pre-B_a) ---
        if (t >= 1 && tid < BM) {
            const float (*sp)[BM] = sPart[(t - 1) & 1];
            float v = bc;
            #pragma unroll
            for (int w = 0; w < 8; ++w) v += sp[w][tid];
            out[brow0 + (t - 1) * BM + tid] = v;
        }

        // --- GEMM1(t): D1[n][m] = W1 . x^T ; epi1 -> h1s ---
        f32x4 acc[4][2];
        #pragma unroll
        for (int mt = 0; mt < 4; ++mt)
            #pragma unroll
            for (int nt = 0; nt < 2; ++nt)
                acc[mt][nt] = (f32x4){0.f, 0.f, 0.f, 0.f};

        #pragma unroll
        for (int ks = 0; ks < 4; ++ks) {
            const int k0 = ks * 32 + q * 8;
            bf16x8 bfr[4];
            #pragma unroll
            for (int mt = 0; mt < 4; ++mt)
                bfr[mt] = *(const bf16x8*)&xs[(mt * 16 + ln) * XS_PITCH + k0];
            #pragma unroll
            for (int mt = 0; mt < 4; ++mt)
                #pragma unroll
                for (int nt = 0; nt < 2; ++nt)
                    acc[mt][nt] = __builtin_amdgcn_mfma_f32_16x16x32_bf16(w1f[ks][nt], bfr[mt], acc[mt][nt], 0, 0, 0);
        }
        #pragma unroll
        for (int nt = 0; nt < 2; ++nt)
            #pragma unroll
            for (int mt = 0; mt < 4; ++mt) {
                bf16x4 v4;
                #pragma unroll
                for (int r = 0; r < 4; ++r) {
                    float v = acc[mt][nt][r] + b1v[nt][r];
                    v = v > 0.f ? v : 0.f;
                    v4[r] = (bf16)v;
                }
                *(bf16x4*)&h1s[(mt * 16 + ln) * H1_PITCH + colw + nt * 16 + q * 4] = v4;
            }
        __syncthreads();   // B_b(t)

        // --- issue next tile's x loads (latency hidden under GEMM2) ---
        float4 pxa0, pxa1, pxb0, pxb1;
        const bool have_next = (t + 1 < NTILES);
        if (have_next) {
            const int n0 = brow0 + (t + 1) * BM;
            const float* s0 = (c0c8 < 12) ? (state  + (size_t)(n0 + c0r) * SDIM + c0c8 * 8)
                                          : (action + (size_t)(n0 + c0r) * ADIM + (c0c8 - 12) * 8);
            const float* s1 = (c1c8 < 12) ? (state  + (size_t)(n0 + c1r) * SDIM + c1c8 * 8)
                                          : (action + (size_t)(n0 + c1r) * ADIM + (c1c8 - 12) * 8);
            pxa0 = ((const float4*)s0)[0]; pxa1 = ((const float4*)s0)[1];
            pxb0 = ((const float4*)s1)[0]; pxb1 = ((const float4*)s1)[1];
        }

        // --- GEMM2(t): D2[n][m] = W2 . h1^T ; epi2 -> sPart[t&1] ---
        #pragma unroll
        for (int mt = 0; mt < 4; ++mt)
            #pragma unroll
            for (int nt = 0; nt < 2; ++nt)
                acc[mt][nt] = (f32x4){0.f, 0.f, 0.f, 0.f};

        #pragma unroll
        for (int ks = 0; ks < 8; ++ks) {
            const int k0 = ks * 32 + q * 8;
            bf16x8 bfr[4];
            #pragma unroll
            for (int mt = 0; mt < 4; ++mt)
                bfr[mt] = *(const bf16x8*)&h1s[(mt * 16 + ln) * H1_PITCH + k0];
            #pragma unroll
            for (int mt = 0; mt < 4; ++mt)
                #pragma unroll
                for (int nt = 0; nt < 2; ++nt)
                    acc[mt][nt] = __builtin_amdgcn_mfma_f32_16x16x32_bf16(w2f[ks][nt], bfr[mt], acc[mt][nt], 0, 0, 0);
        }

        float partial[4];
        #pragma unroll
        for (int mt = 0; mt < 4; ++mt) {
            float p = 0.f;
            #pragma unroll
            for (int nt = 0; nt < 2; ++nt)
                #pragma unroll
                for (int r = 0; r < 4; ++r) {
                    float v = acc[mt][nt][r] + b2v[nt][r];
                    v = v > 0.f ? v : 0.f;
                    p += v * wcv[nt][r];
                }
            partial[mt] = p;
        }
        #pragma unroll
        for (int mt = 0; mt < 4; ++mt) {
            partial[mt] += __shfl_xor(partial[mt], 16, 64);
            partial[mt] += __shfl_xor(partial[mt], 32, 64);
        }
        if (q == 0) {
            #pragma unroll
            for (int mt = 0; mt < 4; ++mt)
                sPart[t & 1][wave][mt * 16 + ln] = partial[mt];
        }

        // --- stage xs(t+1) from the loads issued above ---
        if (have_next) {
            *(bf16x8*)&xs[c0r * XS_PITCH + c0c8 * 8] =
                (bf16x8){(bf16)pxa0.x, (bf16)pxa0.y, (bf16)pxa0.z, (bf16)pxa0.w,
                         (bf16)pxa1.x, (bf16)pxa1.y, (bf16)pxa1.z, (bf16)pxa1.w};
            *(bf16x8*)&xs[c1r * XS_PITCH + c1c8 * 8] =
                (bf16x8){(bf16)pxb0.x, (bf16)pxb0.y, (bf16)pxb0.z, (bf16)pxb0.w,
                         (bf16)pxb1.x, (bf16)pxb1.y, (bf16)pxb1.z, (bf16)pxb1.w};
        }
        __syncthreads();   // B_a(t+1): orders xs writes, sPart writes, h1 reads
    }

    // final out(NTILES-1)
    if (tid < BM) {
        const float (*sp)[BM] = sPart[(NTILES - 1) & 1];
        float v = bc;
        #pragma unroll
        for (int w = 0; w < 8; ++w) v += sp[w][tid];
        out[brow0 + (NTILES - 1) * BM + tid] = v;
    }
}

extern "C" void kernel_launch(void* const* d_in, const int* in_sizes, int n_in,
                              void* d_out, int out_size, void* d_ws, size_t ws_size,
                              hipStream_t stream) {
    const float* state  = (const float*)d_in[0];
    const float* action = (const float*)d_in[1];
    const float* alphas = (const float*)d_in[2];
    const float* W1     = (const float*)d_in[3];
    const float* b1     = (const float*)d_in[4];
    const float* W2     = (const float*)d_in[5];
    const float* b2     = (const float*)d_in[6];
    const float* Wh     = (const float*)d_in[7];
    const float* bh     = (const float*)d_in[8];
    float* out = (float*)d_out;

    bf16*  W1bf = (bf16*)d_ws;                                  // 65536 B
    bf16*  W2bf = (bf16*)((char*)d_ws + 65536);                 // 131072 B
    float* Wc   = (float*)((char*)d_ws + 65536 + 131072);       // 257 * 4 B

    prep_kernel<<<256, 256, 0, stream>>>(W1, W2, alphas, Wh, bh, W1bf, W2bf, Wc);
    critic_kernel<<<B_TOTAL / (BM * NTILES), 512, 0, stream>>>(
        state, action, b1, b2, W1bf, W2bf, Wc, out);
}

// Round 11
// 112.506 us; speedup vs baseline: 1.2932x; 1.0635x over previous
//
#include <hip/hip_runtime.h>
#include <hip/hip_bf16.h>

// CriticREM: out = relu(relu([state|action]W1^T+b1)W2^T+b2) @ Wc^T + bc
//   Wc = sum_h alpha_h * Wh[h], bc = sum_h alpha_h * bh[h]
// B=65536, IN=128, HID=256, NUM_HEADS=200, OUT=1
//
// R11: R10 with the compile fix — pin weight fragments per SCALAR component
//   ("+v" on float4 is unsupported: "tied indirect register inputs").
//   Single dispatch. R7's tile body (best measured: 111.1us total) with the
//   prep kernel folded in:
//   - W1/W2 fp32 -> bf16 fragment conversion per-block, in-register.
//     Frags pinned so the compiler cannot sink/remat them into the loop
//     (R5/R8 failure mode: sunk weights -> VGPR 104/124 -> 2x regression).
//   - Wc collapse per block: 512 threads x (2 half-partials over 200 heads),
//     LDS combine after first barrier; bc via wave-0 shfl reduce.
//   - Saves: prep kernel work + one inter-dispatch gap.
//   Tile loop, pitches, barriers = R7 verbatim (grid 256, NTILES 4).

#define B_TOTAL 65536
#define SDIM 96
#define ADIM 32
#define IN_F 128
#define HID 256
#define NHEADS 200
#define BM 64           // batch rows per tile
#define NTILES 4        // tiles per block (grid 256 = 1 block/CU)
#define XS_PITCH 132    // 66 dw row stride == 2 mod 32: conflict-free class (R2)
#define H1_PITCH 260    // 130 dw == 2 mod 32: measured 0 conflicts (R2)

typedef __bf16 bf16;
typedef __attribute__((ext_vector_type(4))) __bf16 bf16x4;
typedef __attribute__((ext_vector_type(8))) __bf16 bf16x8;
typedef __attribute__((ext_vector_type(4))) float f32x4;

static __device__ __forceinline__ float4 pack_bf16x8_as_f4(float4 a, float4 b) {
    union { bf16x8 h; float4 f; } u;
    u.h = (bf16x8){(bf16)a.x, (bf16)a.y, (bf16)a.z, (bf16)a.w,
                   (bf16)b.x, (bf16)b.y, (bf16)b.z, (bf16)b.w};
    return u.f;
}
static __device__ __forceinline__ bf16x8 as_bf16x8(float4 v) {
    union { float4 f; bf16x8 h; } u;
    u.f = v;
    return u.h;
}
static __device__ __forceinline__ void pin_f4(float4& v) {
    asm volatile("" : "+v"(v.x), "+v"(v.y), "+v"(v.z), "+v"(v.w));
}

// ---- single fused kernel: 512 threads (8 waves), 4 tiles of 64 rows ----
__global__ __launch_bounds__(512, 2) void critic_kernel(
        const float* __restrict__ state, const float* __restrict__ action,
        const float* __restrict__ alphas,
        const float* __restrict__ W1, const float* __restrict__ b1,
        const float* __restrict__ W2, const float* __restrict__ b2,
        const float* __restrict__ Wh, const float* __restrict__ bh,
        float* __restrict__ out) {

    __shared__ bf16  xs[BM * XS_PITCH];     // 16896 B
    __shared__ bf16  h1s[BM * H1_PITCH];    // 33280 B
    __shared__ float sPart[8][BM];          // 2048 B
    __shared__ float sWcP[2][HID];          // 2048 B  (head-half partials)
    __shared__ float sWc[HID + 1];          // 1028 B  ([HID] = bc)   ~55.3 KB

    const int tid  = threadIdx.x;
    const int wave = tid >> 6;      // 0..7
    const int lane = tid & 63;
    const int q    = lane >> 4;     // 0..3
    const int ln   = lane & 15;     // 0..15
    const int colw = wave * 32;     // this wave's 32-hidden-col slice
    const int brow0 = blockIdx.x * (BM * NTILES);

    // ---- preamble: weight fragments from fp32 W1/W2, converted + PINNED ----
    float4 w1s[4][2];   // 32 VGPR (bf16x8 stored as float4)
    #pragma unroll
    for (int ks = 0; ks < 4; ++ks)
        #pragma unroll
        for (int nt = 0; nt < 2; ++nt) {
            const float* p = W1 + (size_t)(colw + nt * 16 + ln) * IN_F + ks * 32 + q * 8;
            w1s[ks][nt] = pack_bf16x8_as_f4(((const float4*)p)[0], ((const float4*)p)[1]);
        }

    float4 w2s[8][2];   // 64 VGPR
    #pragma unroll
    for (int ks = 0; ks < 8; ++ks)
        #pragma unroll
        for (int nt = 0; nt < 2; ++nt) {
            const float* p = W2 + (size_t)(colw + nt * 16 + ln) * HID + ks * 32 + q * 8;
            w2s[ks][nt] = pack_bf16x8_as_f4(((const float4*)p)[0], ((const float4*)p)[1]);
        }

    // pin: value becomes opaque -> compiler cannot sink/remat the loads
    #pragma unroll
    for (int ks = 0; ks < 4; ++ks)
        #pragma unroll
        for (int nt = 0; nt < 2; ++nt)
            pin_f4(w1s[ks][nt]);
    #pragma unroll
    for (int ks = 0; ks < 8; ++ks)
        #pragma unroll
        for (int nt = 0; nt < 2; ++nt)
            pin_f4(w2s[ks][nt]);

    // bias constants: hidden col n = colw + nt*16 + q*4 + r -> float4 loads
    f32x4 b1v[2], b2v[2];
    #pragma unroll
    for (int nt = 0; nt < 2; ++nt) {
        const int n4 = colw + nt * 16 + q * 4;
        b1v[nt] = *(const f32x4*)&b1[n4];
        b2v[nt] = *(const f32x4*)&b2[n4];
    }

    // ---- Wc collapse: thread (half, c) sums 100 heads for col c ----
    {
        const int c    = tid & 255;
        const int half = tid >> 8;
        float p = 0.f;
        #pragma unroll 10
        for (int i = 0; i < 100; ++i) {
            const int h = half * 100 + i;
            p += alphas[h] * Wh[(size_t)h * HID + c];
        }
        sWcP[half][c] = p;
    }
    // bc: wave 0 shfl-reduce over 200 heads
    if (tid < 64) {
        float p = 0.f;
        #pragma unroll
        for (int i = 0; i < 4; ++i) {
            const int h = tid + i * 64;
            if (h < NHEADS) p += alphas[h] * bh[h];
        }
        #pragma unroll
        for (int off = 1; off < 64; off <<= 1)
            p += __shfl_xor(p, off, 64);
        if (tid == 0) sWc[HID] = p;
    }

    // x staging geometry: 512 threads x 2 chunks of 8 fp32 (64 rows x 16 chunks)
    const int c0r  = tid >> 4;
    const int c0c8 = tid & 15;
    const int c1r  = (tid + 512) >> 4;
    const int c1c8 = (tid + 512) & 15;

    // px prefetch for tile 0
    float4 px[2][2];
    {
        const float* s0 = (c0c8 < 12) ? (state  + (size_t)(brow0 + c0r) * SDIM + c0c8 * 8)
                                      : (action + (size_t)(brow0 + c0r) * ADIM + (c0c8 - 12) * 8);
        const float* s1 = (c1c8 < 12) ? (state  + (size_t)(brow0 + c1r) * SDIM + c1c8 * 8)
                                      : (action + (size_t)(brow0 + c1r) * ADIM + (c1c8 - 12) * 8);
        px[0][0] = ((const float4*)s0)[0]; px[0][1] = ((const float4*)s0)[1];
        px[1][0] = ((const float4*)s1)[0]; px[1][1] = ((const float4*)s1)[1];
    }

    for (int t = 0; t < NTILES; ++t) {
        const int row0 = brow0 + t * BM;

        // stage x tile from px regs
        *(bf16x8*)&xs[c0r * XS_PITCH + c0c8 * 8] =
            (bf16x8){(bf16)px[0][0].x, (bf16)px[0][0].y, (bf16)px[0][0].z, (bf16)px[0][0].w,
                     (bf16)px[0][1].x, (bf16)px[0][1].y, (bf16)px[0][1].z, (bf16)px[0][1].w};
        *(bf16x8*)&xs[c1r * XS_PITCH + c1c8 * 8] =
            (bf16x8){(bf16)px[1][0].x, (bf16)px[1][0].y, (bf16)px[1][0].z, (bf16)px[1][0].w,
                     (bf16)px[1][1].x, (bf16)px[1][1].y, (bf16)px[1][1].z, (bf16)px[1][1].w};
        __syncthreads();   // A(t): xs visible (t==0: also sWcP/bc visible)

        // one-time: combine Wc partials (ordered before first wcv use by B(t))
        if (t == 0 && tid < HID)
            sWc[tid] = sWcP[0][tid] + sWcP[1][tid];

        // prefetch NEXT tile's x
        if (t + 1 < NTILES) {
            const int n0 = row0 + BM;
            const float* s0 = (c0c8 < 12) ? (state  + (size_t)(n0 + c0r) * SDIM + c0c8 * 8)
                                          : (action + (size_t)(n0 + c0r) * ADIM + (c0c8 - 12) * 8);
            const float* s1 = (c1c8 < 12) ? (state  + (size_t)(n0 + c1r) * SDIM + c1c8 * 8)
                                          : (action + (size_t)(n0 + c1r) * ADIM + (c1c8 - 12) * 8);
            px[0][0] = ((const float4*)s0)[0]; px[0][1] = ((const float4*)s0)[1];
            px[1][0] = ((const float4*)s1)[0]; px[1][1] = ((const float4*)s1)[1];
        }

        // ---- GEMM1(t): D1[n][m] = W1 . x^T ; epi1 -> h1s ----
        f32x4 acc[4][2];
        #pragma unroll
        for (int mt = 0; mt < 4; ++mt)
            #pragma unroll
            for (int nt = 0; nt < 2; ++nt)
                acc[mt][nt] = (f32x4){0.f, 0.f, 0.f, 0.f};

        #pragma unroll
        for (int ks = 0; ks < 4; ++ks) {
            const int k0 = ks * 32 + q * 8;
            bf16x8 bfr[4];
            #pragma unroll
            for (int mt = 0; mt < 4; ++mt)
                bfr[mt] = *(const bf16x8*)&xs[(mt * 16 + ln) * XS_PITCH + k0];
            #pragma unroll
            for (int mt = 0; mt < 4; ++mt)
                #pragma unroll
                for (int nt = 0; nt < 2; ++nt)
                    acc[mt][nt] = __builtin_amdgcn_mfma_f32_16x16x32_bf16(
                        as_bf16x8(w1s[ks][nt]), bfr[mt], acc[mt][nt], 0, 0, 0);
        }
        #pragma unroll
        for (int nt = 0; nt < 2; ++nt)
            #pragma unroll
            for (int mt = 0; mt < 4; ++mt) {
                bf16x4 v4;
                #pragma unroll
                for (int r = 0; r < 4; ++r) {
                    float v = acc[mt][nt][r] + b1v[nt][r];
                    v = v > 0.f ? v : 0.f;
                    v4[r] = (bf16)v;
                }
                *(bf16x4*)&h1s[(mt * 16 + ln) * H1_PITCH + colw + nt * 16 + q * 4] = v4;
            }
        __syncthreads();   // B(t): h1s visible, sWc visible

        // ---- GEMM2(t): D2[n][m] = W2 . h1^T ; epi2 -> sPart ----
        #pragma unroll
        for (int mt = 0; mt < 4; ++mt)
            #pragma unroll
            for (int nt = 0; nt < 2; ++nt)
                acc[mt][nt] = (f32x4){0.f, 0.f, 0.f, 0.f};

        #pragma unroll
        for (int ks = 0; ks < 8; ++ks) {
            const int k0 = ks * 32 + q * 8;
            bf16x8 bfr[4];
            #pragma unroll
            for (int mt = 0; mt < 4; ++mt)
                bfr[mt] = *(const bf16x8*)&h1s[(mt * 16 + ln) * H1_PITCH + k0];
            #pragma unroll
            for (int mt = 0; mt < 4; ++mt)
                #pragma unroll
                for (int nt = 0; nt < 2; ++nt)
                    acc[mt][nt] = __builtin_amdgcn_mfma_f32_16x16x32_bf16(
                        as_bf16x8(w2s[ks][nt]), bfr[mt], acc[mt][nt], 0, 0, 0);
        }

        // epi2: bias+relu+Wc-dot in-lane; wcv broadcast-read from sWc
        f32x4 wcv[2];
        #pragma unroll
        for (int nt = 0; nt < 2; ++nt)
            wcv[nt] = *(const f32x4*)&sWc[colw + nt * 16 + q * 4];

        float partial[4];
        #pragma unroll
        for (int mt = 0; mt < 4; ++mt) {
            float p = 0.f;
            #pragma unroll
            for (int nt = 0; nt < 2; ++nt)
                #pragma unroll
                for (int r = 0; r < 4; ++r) {
                    float v = acc[mt][nt][r] + b2v[nt][r];
                    v = v > 0.f ? v : 0.f;
                    p += v * wcv[nt][r];
                }
            partial[mt] = p;
        }
        #pragma unroll
        for (int mt = 0; mt < 4; ++mt) {
            partial[mt] += __shfl_xor(partial[mt], 16, 64);
            partial[mt] += __shfl_xor(partial[mt], 32, 64);
        }
        if (q == 0) {
            #pragma unroll
            for (int mt = 0; mt < 4; ++mt)
                sPart[wave][mt * 16 + ln] = partial[mt];
        }
        __syncthreads();   // C(t): sPart visible; next tile may overwrite xs/h1s

        if (tid < BM) {
            float v = sWc[HID];
            #pragma unroll
            for (int w = 0; w < 8; ++w) v += sPart[w][tid];
            out[row0 + tid] = v;
        }
    }
}

extern "C" void kernel_launch(void* const* d_in, const int* in_sizes, int n_in,
                              void* d_out, int out_size, void* d_ws, size_t ws_size,
                              hipStream_t stream) {
    const float* state  = (const float*)d_in[0];
    const float* action = (const float*)d_in[1];
    const float* alphas = (const float*)d_in[2];
    const float* W1     = (const float*)d_in[3];
    const float* b1     = (const float*)d_in[4];
    const float* W2     = (const float*)d_in[5];
    const float* b2     = (const float*)d_in[6];
    const float* Wh     = (const float*)d_in[7];
    const float* bh     = (const float*)d_in[8];
    float* out = (float*)d_out;

    critic_kernel<<<B_TOTAL / (BM * NTILES), 512, 0, stream>>>(
        state, action, alphas, W1, b1, W2, b2, Wh, bh, out);
}